// Round 10
// baseline (205.058 us; speedup 1.0000x reference)
//
#include <hip/hip_runtime.h>

#define N_NODES 50000
#define N_EDGES 800000
#define F_IN    128
#define HID     32
#define HEADS   4
#define OUT_C   16

#define NBKT 196      // buckets = dst>>8 ; 196*256 = 50176 >= N_NODES
#define CAP  5120     // per-bucket capacity; mean 4082
#define EPB  4096     // edges per bucketA block; 196 blocks cover 802816
#define NB64 782      // ceil(N_NODES/64)

typedef __attribute__((ext_vector_type(8))) short bf16x8;   // 8 bf16 = 4 VGPR (MFMA A/B frag)
typedef __attribute__((ext_vector_type(4))) float f32x4;    // MFMA C/D frag

// bf16 helpers (RNE)
__device__ __forceinline__ unsigned short f2bf(float f) {
    unsigned int u = __float_as_uint(f);
    u += 0x7FFFu + ((u >> 16) & 1u);
    return (unsigned short)(u >> 16);
}
__device__ __forceinline__ float bf_lo(unsigned int u) { return __uint_as_float(u << 16); }
__device__ __forceinline__ float bf_hi(unsigned int u) { return __uint_as_float(u & 0xFFFF0000u); }
__device__ __forceinline__ float bf2f(unsigned short s) {
    return __uint_as_float(((unsigned int)s) << 16);
}

__device__ __forceinline__ float edge_w(float asv, float adv) {
    float v = asv + adv;
    v = (v > 0.f) ? v : 0.2f * v;        // leaky_relu(0.2)
    return __expf(v);                    // softmax shift-invariant; logits O(1)
}

// ================================================================ F1 = {h0 = x@Wemb+bemb (regs only); h0b bf16;
// as/ad via factored alpha: as[n,h] = h0[n]·vsrc[:,h]} ∪ bucketA.
__global__ __launch_bounds__(256) void k_F1(const float* __restrict__ x,
                                            const float* __restrict__ Wemb,
                                            const float* __restrict__ bemb,
                                            const float* __restrict__ W1,
                                            const float* __restrict__ a_src,
                                            const float* __restrict__ a_dst,
                                            unsigned short* __restrict__ h0b,
                                            float* __restrict__ as, float* __restrict__ ad,
                                            const int* __restrict__ ei,
                                            int* __restrict__ gcnt,
                                            unsigned int* __restrict__ pairs) {
    __shared__ float xs[64][132];
    __shared__ float Wl[F_IN][HID];
    __shared__ float bl[HID];
    __shared__ float vs[HID][4];       // vsrc[k][h]
    __shared__ float vd[HID][4];       // vdst[k][h]
    __shared__ int hist[NBKT];
    __shared__ int base[NBKT];
    int t = threadIdx.x;
    if (blockIdx.x < NB64) {
        int node0 = blockIdx.x * 64;
        if (t < HID) bl[t] = bemb[t];
        {
            int k = (t & 127) >> 2, h = t & 3;
            const float* wrow = W1 + k * 128 + h * 32;
            const float* arow = ((t < 128) ? a_src : a_dst) + h * 32;
            float accv = 0.f;
            #pragma unroll
            for (int c2 = 0; c2 < 32; c2++) accv += wrow[c2] * arow[c2];
            if (t < 128) vs[k][h] = accv; else vd[k][h] = accv;
        }
        #pragma unroll
        for (int it = 0; it < 4; it++) {
            int idx = it * 256 + t;
            *(float4*)((float*)Wl + idx * 4) = *(const float4*)(Wemb + idx * 4);
        }
        #pragma unroll
        for (int it = 0; it < 8; it++) {
            int idx = it * 256 + t;
            int row = idx >> 5, c4 = idx & 31;
            float4 v = make_float4(0.f, 0.f, 0.f, 0.f);
            if (node0 + row < N_NODES) v = *(const float4*)(x + (size_t)(node0 + row) * F_IN + c4 * 4);
            *(float4*)&xs[row][c4 * 4] = v;
        }
        __syncthreads();
        int c = t & 7, g = t >> 3;
        float acc[2][4] = {};
        for (int k = 0; k < F_IN; k++) {
            float4 w4 = *(const float4*)&Wl[k][c * 4];
            #pragma unroll
            for (int n = 0; n < 2; n++) {
                float xv = xs[g * 2 + n][k];
                acc[n][0] += xv * w4.x; acc[n][1] += xv * w4.y;
                acc[n][2] += xv * w4.z; acc[n][3] += xv * w4.w;
            }
        }
        float ps[2][4], pd[2][4];
        #pragma unroll
        for (int n = 0; n < 2; n++) {
            float o0 = acc[n][0] + bl[c * 4];
            float o1 = acc[n][1] + bl[c * 4 + 1];
            float o2 = acc[n][2] + bl[c * 4 + 2];
            float o3 = acc[n][3] + bl[c * 4 + 3];
            int node = node0 + g * 2 + n;
            if (node < N_NODES) {
                ushort4 ob;
                ob.x = f2bf(o0); ob.y = f2bf(o1); ob.z = f2bf(o2); ob.w = f2bf(o3);
                *(ushort4*)(h0b + (size_t)node * HID + c * 4) = ob;
            }
            #pragma unroll
            for (int h = 0; h < 4; h++) {
                ps[n][h] = o0 * vs[c * 4][h] + o1 * vs[c * 4 + 1][h]
                         + o2 * vs[c * 4 + 2][h] + o3 * vs[c * 4 + 3][h];
                pd[n][h] = o0 * vd[c * 4][h] + o1 * vd[c * 4 + 1][h]
                         + o2 * vd[c * 4 + 2][h] + o3 * vd[c * 4 + 3][h];
            }
        }
        #pragma unroll
        for (int mask = 1; mask <= 4; mask <<= 1) {
            #pragma unroll
            for (int n = 0; n < 2; n++) {
                #pragma unroll
                for (int h = 0; h < 4; h++) {
                    ps[n][h] += __shfl_xor(ps[n][h], mask, 64);
                    pd[n][h] += __shfl_xor(pd[n][h], mask, 64);
                }
            }
        }
        if (c == 0) {
            #pragma unroll
            for (int n = 0; n < 2; n++) {
                int node = node0 + g * 2 + n;
                if (node < N_NODES) {
                    *(float4*)(as + node * 4) = make_float4(ps[n][0], ps[n][1], ps[n][2], ps[n][3]);
                    *(float4*)(ad + node * 4) = make_float4(pd[n][0], pd[n][1], pd[n][2], pd[n][3]);
                }
            }
        }
    } else {
        int e0 = (blockIdx.x - NB64) * EPB;
        for (int i = t; i < NBKT; i += 256) hist[i] = 0;
        __syncthreads();
        unsigned int p[16];
        int bb[16];
        #pragma unroll
        for (int i = 0; i < 16; i++) {
            int e = e0 + i * 256 + t;
            bb[i] = -1;
            if (e < N_EDGES) {
                int s = ei[e], d = ei[N_EDGES + e];
                p[i] = ((unsigned int)s << 8) | (unsigned int)(d & 255);
                bb[i] = d >> 8;
                atomicAdd(&hist[bb[i]], 1);
            }
        }
        __syncthreads();
        for (int i = t; i < NBKT; i += 256) {
            int c = hist[i];
            base[i] = i * CAP + (c ? atomicAdd(&gcnt[i], c) : 0);
            hist[i] = 0;
        }
        __syncthreads();
        #pragma unroll
        for (int i = 0; i < 16; i++) {
            if (bb[i] >= 0) {
                int off = atomicAdd(&hist[bb[i]], 1);
                pairs[base[bb[i]] + off] = p[i];
            }
        }
    }
}

// ================================================================ F2 = bucketB only (CSR build from pairs)
__global__ __launch_bounds__(256) void k_F2(const unsigned int* __restrict__ pairs,
                                            const int* __restrict__ gcnt,
                                            int* __restrict__ rowptr,
                                            int* __restrict__ esrc) {
    __shared__ int cnt[256];
    __shared__ int cur[256];
    __shared__ int wsum[4];
    int t = threadIdx.x;
    int b = blockIdx.x;
    int lane = t & 63, wv = t >> 6;
    int v0 = (t < NBKT && t < b) ? gcnt[t] : 0;
    #pragma unroll
    for (int mask = 1; mask < 64; mask <<= 1) v0 += __shfl_xor(v0, mask, 64);
    if (lane == 0) wsum[wv] = v0;
    __syncthreads();
    int base = wsum[0] + wsum[1] + wsum[2] + wsum[3];
    int n0 = b << 8;
    int cntb = gcnt[b];
    int s0 = b * CAP;
    cnt[t] = 0;
    __syncthreads();
    for (int i = t; i < cntb; i += 256) atomicAdd(&cnt[pairs[s0 + i] & 255], 1);
    __syncthreads();
    int v = cnt[t], x = v;
    #pragma unroll
    for (int off = 1; off < 64; off <<= 1) { int y = __shfl_up(x, off, 64); if (lane >= off) x += y; }
    __syncthreads();
    if (lane == 63) wsum[wv] = x;
    __syncthreads();
    int add = 0;
    for (int j = 0; j < wv; j++) add += wsum[j];
    int excl = base + (x - v) + add;
    cur[t] = excl;
    if (n0 + t < N_NODES) rowptr[n0 + t] = excl;
    if (b == 0 && t == 0) rowptr[N_NODES] = N_EDGES;
    __syncthreads();
    for (int i = t; i < cntb; i += 256) {
        unsigned int p = pairs[s0 + i];
        int pos = atomicAdd(&cur[p & 255], 1);
        esrc[pos] = (int)(p >> 8);
    }
}

// ================================================================ layer-1 gather, multi-row loads: lane (q=lane>>4,
// cp=lane&15) loads the cp-th dword of edge-slot 4jj+q's row — 1 load instruction serves 4 edges (was 4x-redundant
// 16 loads/group). Per-head partials merged once per node by a 2-round butterfly over q.
__global__ __launch_bounds__(256) void k_gather1(const int* __restrict__ esrc,
                                                 const int* __restrict__ rowptr,
                                                 const unsigned int* __restrict__ h0b,  // bf16x2 [N,16] dwords
                                                 const float* __restrict__ as,
                                                 const float* __restrict__ ad,
                                                 unsigned int* __restrict__ awb) {      // bf16x2 [N,64] dwords
    int t = threadIdx.x;
    int node = blockIdx.x * 4 + (t >> 6);
    int lane = t & 63;
    int q = lane >> 4;                 // edge sub-slot; doubles as output head index
    int cp = lane & 15;                // k-pair within the 64B h0 row
    int s16 = lane >> 2;               // weight slot 0..15
    int h4 = lane & 3;                 // weight head 0..3
    int cpb = cp * 4;
    int qb = q * 16;                   // bpermute byte base: slot (4jj+q) lives at lane (4jj+q)*4
    int beg = rowptr[node], end = rowptr[node + 1];
    float ad_w = ad[node * 4 + h4];
    float ax0 = 0.f, ax1 = 0.f, ax2 = 0.f, ax3 = 0.f;
    float ay0 = 0.f, ay1 = 0.f, ay2 = 0.f, ay3 = 0.f;
    float sacc = 0.f;
    const char* hc = (const char*)h0b;
    for (int k = beg; k < end; k += 16) {
        int idx = k + s16;
        int sm = esrc[min(idx, end - 1)];
        float wm = edge_w(as[sm * 4 + h4], ad_w);
        if (idx >= end) wm = 0.f;                 // tail masking at source lane
        sacc += wm;
        int wmi = __float_as_int(wm);
        // row indices of my 4 edges (slots q, 4+q, 8+q, 12+q)
        int r0 = __builtin_amdgcn_ds_bpermute(qb,       sm);
        int r1 = __builtin_amdgcn_ds_bpermute(qb + 64,  sm);
        int r2 = __builtin_amdgcn_ds_bpermute(qb + 128, sm);
        int r3 = __builtin_amdgcn_ds_bpermute(qb + 192, sm);
        unsigned int u0 = *(const unsigned int*)(hc + (size_t)(unsigned)r0 * 64 + cpb);
        unsigned int u1 = *(const unsigned int*)(hc + (size_t)(unsigned)r1 * 64 + cpb);
        unsigned int u2 = *(const unsigned int*)(hc + (size_t)(unsigned)r2 * 64 + cpb);
        unsigned int u3 = *(const unsigned int*)(hc + (size_t)(unsigned)r3 * 64 + cpb);
#define BW(J,H) __int_as_float(__builtin_amdgcn_ds_bpermute(qb + (J)*64 + (H)*4, wmi))
        float w00 = BW(0,0), w01 = BW(0,1), w02 = BW(0,2), w03 = BW(0,3);
        float w10 = BW(1,0), w11 = BW(1,1), w12 = BW(1,2), w13 = BW(1,3);
        float w20 = BW(2,0), w21 = BW(2,1), w22 = BW(2,2), w23 = BW(2,3);
        float w30 = BW(3,0), w31 = BW(3,1), w32 = BW(3,2), w33 = BW(3,3);
#undef BW
        float la0 = bf_lo(u0), hb0 = bf_hi(u0);
        float la1 = bf_lo(u1), hb1 = bf_hi(u1);
        float la2 = bf_lo(u2), hb2 = bf_hi(u2);
        float la3 = bf_lo(u3), hb3 = bf_hi(u3);
        ax0 += la0 * w00 + la1 * w10 + la2 * w20 + la3 * w30;
        ay0 += hb0 * w00 + hb1 * w10 + hb2 * w20 + hb3 * w30;
        ax1 += la0 * w01 + la1 * w11 + la2 * w21 + la3 * w31;
        ay1 += hb0 * w01 + hb1 * w11 + hb2 * w21 + hb3 * w31;
        ax2 += la0 * w02 + la1 * w12 + la2 * w22 + la3 * w32;
        ay2 += hb0 * w02 + hb1 * w12 + hb2 * w22 + hb3 * w32;
        ax3 += la0 * w03 + la1 * w13 + la2 * w23 + la3 * w33;
        ay3 += hb0 * w03 + hb1 * w13 + hb2 * w23 + hb3 * w33;
    }
    // s: reduce over the 16 slots (lanes sharing h4 differ in bits 2..5)
    #pragma unroll
    for (int m = 4; m <= 32; m <<= 1) sacc += __shfl_xor(sacc, m, 64);
    // merge per-head partials over the 4 q-subsets
    ax0 += __shfl_xor(ax0, 16, 64); ax0 += __shfl_xor(ax0, 32, 64);
    ax1 += __shfl_xor(ax1, 16, 64); ax1 += __shfl_xor(ax1, 32, 64);
    ax2 += __shfl_xor(ax2, 16, 64); ax2 += __shfl_xor(ax2, 32, 64);
    ax3 += __shfl_xor(ax3, 16, 64); ax3 += __shfl_xor(ax3, 32, 64);
    ay0 += __shfl_xor(ay0, 16, 64); ay0 += __shfl_xor(ay0, 32, 64);
    ay1 += __shfl_xor(ay1, 16, 64); ay1 += __shfl_xor(ay1, 32, 64);
    ay2 += __shfl_xor(ay2, 16, 64); ay2 += __shfl_xor(ay2, 32, 64);
    ay3 += __shfl_xor(ay3, 16, 64); ay3 += __shfl_xor(ay3, 32, 64);
    float axf = (q == 0) ? ax0 : (q == 1) ? ax1 : (q == 2) ? ax2 : ax3;
    float ayf = (q == 0) ? ay0 : (q == 1) ? ay1 : (q == 2) ? ay2 : ay3;
    // s for head q sits (fully slot-reduced) in lane q
    float sT = __int_as_float(__builtin_amdgcn_ds_bpermute(q * 4, __float_as_int(sacc)));
    float rs = 1.0f / (sT + 1e-16f);
    awb[(size_t)node * 64 + lane] = ((unsigned int)f2bf(ayf * rs) << 16) | (unsigned int)f2bf(axf * rs);
}

// ================================================================ k_h12: fused layer-1 epilogue + layer-2 GEMM (MFMA).
__global__ __launch_bounds__(256) void k_h12(const unsigned int* __restrict__ awb,  // [N,64] dwords
                                             const float* __restrict__ W1,          // [32][128] f32
                                             const float* __restrict__ b1,          // [128]
                                             const float* __restrict__ W2,          // [128][64] f32
                                             const float* __restrict__ a_src,
                                             const float* __restrict__ a_dst,
                                             unsigned short* __restrict__ h2,
                                             float* __restrict__ as, float* __restrict__ ad) {
    __shared__ unsigned int xsu[64][68];       // pass-1 A tile (awb); reused as out1 tile (ushort [64][136])
    __shared__ unsigned short w1t[128][40];    // [outch][k_h0] bf16 (W1^T)
    __shared__ unsigned short w2t[64][136];    // [n][k] bf16 (W2^T)
    __shared__ float b1s[128];
    int t = threadIdx.x;
    int node0 = blockIdx.x * 64;
    if (t < 128) b1s[t] = b1[t];
    #pragma unroll
    for (int it = 0; it < 4; it++) {
        int idx = it * 256 + t;
        int row = idx >> 4, c4 = idx & 15;
        uint4 v = make_uint4(0u, 0u, 0u, 0u);
        if (node0 + row < N_NODES) v = *(const uint4*)(awb + (size_t)(node0 + row) * 64 + c4 * 4);
        *(uint4*)&xsu[row][c4 * 4] = v;
    }
    #pragma unroll
    for (int it = 0; it < 16; it++) {
        int idx = it * 256 + t;
        int k = idx >> 7, n = idx & 127;
        w1t[n][k] = f2bf(W1[idx]);
    }
    #pragma unroll
    for (int it = 0; it < 8; it++) {
        int idx = it * 256 + t;
        int k = idx >> 4, n4 = idx & 15;
        float4 w = *(const float4*)(W2 + k * 64 + n4 * 4);
        w2t[n4 * 4 + 0][k] = f2bf(w.x);
        w2t[n4 * 4 + 1][k] = f2bf(w.y);
        w2t[n4 * 4 + 2][k] = f2bf(w.z);
        w2t[n4 * 4 + 3][k] = f2bf(w.w);
    }
    __syncthreads();
    int lane = t & 63, wv = t >> 6;
    int lrow = lane & 15, lk = lane >> 4;
    const char* abase = (const char*)&xsu[wv * 16 + lrow][0];
    f32x4 o1[8];
    #pragma unroll
    for (int nt = 0; nt < 8; nt++) {
        int kt = nt >> 1;
        bf16x8 af = *(const bf16x8*)(abase + kt * 64 + lk * 16);
        bf16x8 bf1 = *(const bf16x8*)((const char*)&w1t[nt * 16 + lrow][0] + lk * 16);
        f32x4 z = {};
        o1[nt] = __builtin_amdgcn_mfma_f32_16x16x32_bf16(af, bf1, z, 0, 0, 0);
    }
    __syncthreads();
    unsigned short* o1t = (unsigned short*)&xsu[0][0];
    #pragma unroll
    for (int nt = 0; nt < 8; nt++) {
        float bb = b1s[nt * 16 + lrow];
        #pragma unroll
        for (int r = 0; r < 4; r++) {
            int noderow = wv * 16 + lk * 4 + r;
            float v = o1[nt][r] + bb;
            v = (v > 0.f) ? v : (__expf(v) - 1.0f);   // ELU
            o1t[noderow * 136 + nt * 16 + lrow] = f2bf(v);
        }
    }
    __syncthreads();
    f32x4 acc[4] = {};
    const char* xbase = (const char*)&o1t[(wv * 16 + lrow) * 136];
    #pragma unroll
    for (int kt = 0; kt < 4; kt++) {
        bf16x8 af = *(const bf16x8*)(xbase + kt * 64 + lk * 16);
        #pragma unroll
        for (int h = 0; h < 4; h++) {
            bf16x8 bfr = *(const bf16x8*)((const char*)&w2t[h * 16 + lrow][0] + kt * 64 + lk * 16);
            acc[h] = __builtin_amdgcn_mfma_f32_16x16x32_bf16(af, bfr, acc[h], 0, 0, 0);
        }
    }
    float av[4], dv[4];
    #pragma unroll
    for (int h = 0; h < 4; h++) { av[h] = a_src[h * 16 + lrow]; dv[h] = a_dst[h * 16 + lrow]; }
    #pragma unroll
    for (int r = 0; r < 4; r++) {
        int node = node0 + wv * 16 + lk * 4 + r;
        float psh[4], pdh[4];
        #pragma unroll
        for (int h = 0; h < 4; h++) {
            float v = acc[h][r];
            if (node < N_NODES) h2[(size_t)node * 64 + h * 16 + lrow] = f2bf(v);
            float p = v * av[h], qv = v * dv[h];
            #pragma unroll
            for (int mask = 1; mask < 16; mask <<= 1) {
                p += __shfl_xor(p, mask, 64);
                qv += __shfl_xor(qv, mask, 64);
            }
            psh[h] = p; pdh[h] = qv;
        }
        if (lrow == 0 && node < N_NODES) {
            *(float4*)(as + node * 4) = make_float4(psh[0], psh[1], psh[2], psh[3]);
            *(float4*)(ad + node * 4) = make_float4(pdh[0], pdh[1], pdh[2], pdh[3]);
        }
    }
}

// ================================================================ layer-2 gather, multi-row loads: lane (q,cp) loads
// 8B (channels 4cp..4cp+3) of edge-slot 4jj+q's row — 4 loads + 4 idx-bpermutes + 4 w-bpermutes per 16-edge group
// (was 16/16/16). Channel partials merged over q, then redistributed for the head-mean/log_softmax epilogue.
__global__ __launch_bounds__(256) void k_gather2(const int* __restrict__ esrc,
                                                 const int* __restrict__ rowptr,
                                                 const unsigned short* __restrict__ h2,  // bf16 [N,64]
                                                 const float* __restrict__ as,
                                                 const float* __restrict__ ad,
                                                 const float* __restrict__ b2,
                                                 float* __restrict__ out) {
    int t = threadIdx.x;
    int node = blockIdx.x * 4 + (t >> 6);
    int lane = t & 63;
    int q = lane >> 4;                 // edge sub-slot
    int cp = lane & 15;                // channel quad: channels 4cp..4cp+3
    int hcd = cp >> 2;                 // head of my 4 channels
    int s16 = lane >> 2;               // weight slot
    int h4 = lane & 3;                 // weight head
    int qb = q * 16;
    int wb = qb + hcd * 4;             // w-bpermute base for (slot 4jj+q, head hcd)
    int beg = rowptr[node], end = rowptr[node + 1];
    float ad_w = ad[node * 4 + h4];
    float a0 = 0.f, a1 = 0.f, a2 = 0.f, a3 = 0.f, sacc = 0.f;
    const char* pc = (const char*)h2;
    for (int k = beg; k < end; k += 16) {
        int idx = k + s16;
        int sm = esrc[min(idx, end - 1)];
        float wm = edge_w(as[sm * 4 + h4], ad_w);
        if (idx >= end) wm = 0.f;
        sacc += wm;
        int wmi = __float_as_int(wm);
        int r0 = __builtin_amdgcn_ds_bpermute(qb,       sm);
        int r1 = __builtin_amdgcn_ds_bpermute(qb + 64,  sm);
        int r2 = __builtin_amdgcn_ds_bpermute(qb + 128, sm);
        int r3 = __builtin_amdgcn_ds_bpermute(qb + 192, sm);
        uint2 u0 = *(const uint2*)(pc + (size_t)(unsigned)r0 * 128 + cp * 8);
        uint2 u1 = *(const uint2*)(pc + (size_t)(unsigned)r1 * 128 + cp * 8);
        uint2 u2 = *(const uint2*)(pc + (size_t)(unsigned)r2 * 128 + cp * 8);
        uint2 u3 = *(const uint2*)(pc + (size_t)(unsigned)r3 * 128 + cp * 8);
        float w0 = __int_as_float(__builtin_amdgcn_ds_bpermute(wb,       wmi));
        float w1 = __int_as_float(__builtin_amdgcn_ds_bpermute(wb + 64,  wmi));
        float w2 = __int_as_float(__builtin_amdgcn_ds_bpermute(wb + 128, wmi));
        float w3 = __int_as_float(__builtin_amdgcn_ds_bpermute(wb + 192, wmi));
        a0 += bf_lo(u0.x) * w0 + bf_lo(u1.x) * w1 + bf_lo(u2.x) * w2 + bf_lo(u3.x) * w3;
        a1 += bf_hi(u0.x) * w0 + bf_hi(u1.x) * w1 + bf_hi(u2.x) * w2 + bf_hi(u3.x) * w3;
        a2 += bf_lo(u0.y) * w0 + bf_lo(u1.y) * w1 + bf_lo(u2.y) * w2 + bf_lo(u3.y) * w3;
        a3 += bf_hi(u0.y) * w0 + bf_hi(u1.y) * w1 + bf_hi(u2.y) * w2 + bf_hi(u3.y) * w3;
    }
    // s: reduce over slots; then channel partials over q
    #pragma unroll
    for (int m = 4; m <= 32; m <<= 1) sacc += __shfl_xor(sacc, m, 64);
    a0 += __shfl_xor(a0, 16, 64); a0 += __shfl_xor(a0, 32, 64);
    a1 += __shfl_xor(a1, 16, 64); a1 += __shfl_xor(a1, 32, 64);
    a2 += __shfl_xor(a2, 16, 64); a2 += __shfl_xor(a2, 32, 64);
    a3 += __shfl_xor(a3, 16, 64); a3 += __shfl_xor(a3, 32, 64);
    float sT = __int_as_float(__builtin_amdgcn_ds_bpermute(hcd * 4, sacc == sacc ? __float_as_int(sacc) : 0));
    float rs = 1.0f / (sT + 1e-16f);
    a0 *= rs; a1 *= rs; a2 *= rs; a3 *= rs;
    // redistribute: lane j takes channel j (element j&3 from lane j>>2)
    int ra = (lane >> 2) * 4;
    float t0 = __int_as_float(__builtin_amdgcn_ds_bpermute(ra, __float_as_int(a0)));
    float t1 = __int_as_float(__builtin_amdgcn_ds_bpermute(ra, __float_as_int(a1)));
    float t2 = __int_as_float(__builtin_amdgcn_ds_bpermute(ra, __float_as_int(a2)));
    float t3 = __int_as_float(__builtin_amdgcn_ds_bpermute(ra, __float_as_int(a3)));
    int e = lane & 3;
    float v = (e == 0) ? t0 : (e == 1) ? t1 : (e == 2) ? t2 : t3;
    v += __shfl_xor(v, 16, 64);          // mean over 4 heads
    v += __shfl_xor(v, 32, 64);
    v = v * 0.25f + b2[lane & 15];
    float m = v;                         // log_softmax over 16 classes
    #pragma unroll
    for (int mask = 1; mask < 16; mask <<= 1) m = fmaxf(m, __shfl_xor(m, mask, 64));
    float ex = __expf(v - m);
    float se = ex;
    #pragma unroll
    for (int mask = 1; mask < 16; mask <<= 1) se += __shfl_xor(se, mask, 64);
    float res = (v - m) - __logf(se);
    if (lane < 16) out[(size_t)node * 16 + lane] = res;
}

// ================================================================ host
extern "C" void kernel_launch(void* const* d_in, const int* in_sizes, int n_in,
                              void* d_out, int out_size, void* d_ws, size_t ws_size,
                              hipStream_t stream) {
    const float* x      = (const float*)d_in[0];
    const int*   ei     = (const int*)d_in[1];
    const float* Wemb   = (const float*)d_in[2];
    const float* bemb   = (const float*)d_in[3];
    const float* W1     = (const float*)d_in[4];
    const float* a_src1 = (const float*)d_in[5];
    const float* a_dst1 = (const float*)d_in[6];
    const float* b1     = (const float*)d_in[7];
    const float* W2     = (const float*)d_in[8];
    const float* a_src2 = (const float*)d_in[9];
    const float* a_dst2 = (const float*)d_in[10];
    const float* b2     = (const float*)d_in[11];
    float* out = (float*)d_out;

    char* ws = (char*)d_ws;
    size_t off = 0;
    auto alloc = [&](size_t bytes) { char* p = ws + off; off += (bytes + 255) & ~size_t(255); return p; };
    unsigned short* h2b   = (unsigned short*)alloc((size_t)N_NODES * 64 * 2);   // [N,64] bf16
    unsigned int*   awb   = (unsigned int*)alloc((size_t)N_NODES * 64 * 4);     // bf16x2 [N,128] aggregates
    unsigned short* h0b = (unsigned short*)alloc((size_t)N_NODES * HID * 2);    // [N,32] bf16
    int*          esrc  = (int*)alloc((size_t)N_EDGES * 4 + 64);
    unsigned int* pairs = (unsigned int*)alloc((size_t)NBKT * CAP * 4);
    float* as     = (float*)alloc((size_t)N_NODES * 4 * 4);
    float* ad     = (float*)alloc((size_t)N_NODES * 4 * 4);
    int*   rowptr = (int*)alloc((size_t)(N_NODES + 1) * 4);
    int*   gcnt   = (int*)alloc((size_t)NBKT * 4);

    const int GB = N_NODES / 4;    // 12500

    hipMemsetAsync(gcnt, 0, (size_t)NBKT * 4, stream);
    k_F1<<<NB64 + NBKT, 256, 0, stream>>>(x, Wemb, bemb, W1, a_src1, a_dst1,
                                          h0b, as, ad, ei, gcnt, pairs);
    k_F2<<<NBKT, 256, 0, stream>>>(pairs, gcnt, rowptr, esrc);
    k_gather1<<<GB, 256, 0, stream>>>(esrc, rowptr, (const unsigned int*)h0b, as, ad, awb);
    k_h12<<<NB64, 256, 0, stream>>>(awb, W1, b1, W2, a_src2, a_dst2, h2b, as, ad);
    k_gather2<<<GB, 256, 0, stream>>>(esrc, rowptr, h2b, as, ad, b2, out);
}

// Round 11
// 188.799 us; speedup vs baseline: 1.0861x; 1.0861x over previous
//
#include <hip/hip_runtime.h>

#define N_NODES 50000
#define N_EDGES 800000
#define F_IN    128
#define HID     32
#define HEADS   4
#define OUT_C   16

#define NBKT 196      // buckets = dst>>8 ; 196*256 = 50176 >= N_NODES
#define CAP  5120     // per-bucket capacity; mean 4082
#define EPB  4096     // edges per bucketA block; 196 blocks cover 802816
#define NB64 782      // ceil(N_NODES/64)

typedef __attribute__((ext_vector_type(8))) short bf16x8;   // 8 bf16 = 4 VGPR (MFMA A/B frag)
typedef __attribute__((ext_vector_type(4))) float f32x4;    // MFMA C/D frag

// bf16 helpers (RNE)
__device__ __forceinline__ unsigned short f2bf(float f) {
    unsigned int u = __float_as_uint(f);
    u += 0x7FFFu + ((u >> 16) & 1u);
    return (unsigned short)(u >> 16);
}
__device__ __forceinline__ float bf_lo(unsigned int u) { return __uint_as_float(u << 16); }
__device__ __forceinline__ float bf_hi(unsigned int u) { return __uint_as_float(u & 0xFFFF0000u); }
__device__ __forceinline__ float bf2f(unsigned short s) {
    return __uint_as_float(((unsigned int)s) << 16);
}

__device__ __forceinline__ float edge_w(float asv, float adv) {
    float v = asv + adv;
    v = (v > 0.f) ? v : 0.2f * v;        // leaky_relu(0.2)
    return __expf(v);                    // softmax shift-invariant; logits O(1)
}

// ================================================================ F1 = {h0 = x@Wemb+bemb via MFMA bf16 (f32 acc);
// h0b bf16 write; as/ad via factored alpha from C/D fragments} ∪ bucketA.
__global__ __launch_bounds__(256) void k_F1(const float* __restrict__ x,
                                            const float* __restrict__ Wemb,
                                            const float* __restrict__ bemb,
                                            const float* __restrict__ W1,
                                            const float* __restrict__ a_src,
                                            const float* __restrict__ a_dst,
                                            unsigned short* __restrict__ h0b,
                                            float* __restrict__ as, float* __restrict__ ad,
                                            const int* __restrict__ ei,
                                            int* __restrict__ gcnt,
                                            unsigned int* __restrict__ pairs) {
    __shared__ unsigned short xsb[64][136];    // x tile bf16, row 272B
    __shared__ unsigned short wet[HID][136];   // Wemb^T bf16 [col][k], row 272B
    __shared__ float bl[HID];
    __shared__ float vs[HID][4];       // vsrc[k][h] = sum_c W1[k][h*32+c]*a_src[h*32+c]
    __shared__ float vd[HID][4];
    __shared__ int hist[NBKT];
    __shared__ int base[NBKT];
    int t = threadIdx.x;
    if (blockIdx.x < NB64) {
        int node0 = blockIdx.x * 64;
        if (t < HID) bl[t] = bemb[t];
        // ---- factored alpha vectors
        {
            int k = (t & 127) >> 2, h = t & 3;
            const float* wrow = W1 + k * 128 + h * 32;
            const float* arow = ((t < 128) ? a_src : a_dst) + h * 32;
            float accv = 0.f;
            #pragma unroll
            for (int c2 = 0; c2 < 32; c2++) accv += wrow[c2] * arow[c2];
            if (t < 128) vs[k][h] = accv; else vd[k][h] = accv;
        }
        // ---- stage Wemb^T bf16: Wemb [128][32] row-major -> wet[col][k]
        #pragma unroll
        for (int it = 0; it < 4; it++) {
            int idx = it * 256 + t;            // 1024 float4 = 4096 elems
            int k = idx >> 3, c4 = idx & 7;
            float4 w = *(const float4*)(Wemb + k * HID + c4 * 4);
            wet[c4 * 4 + 0][k] = f2bf(w.x);
            wet[c4 * 4 + 1][k] = f2bf(w.y);
            wet[c4 * 4 + 2][k] = f2bf(w.z);
            wet[c4 * 4 + 3][k] = f2bf(w.w);
        }
        // ---- stage x bf16: [64][128]
        #pragma unroll
        for (int it = 0; it < 8; it++) {
            int idx = it * 256 + t;
            int row = idx >> 5, c4 = idx & 31;
            float4 v = make_float4(0.f, 0.f, 0.f, 0.f);
            if (node0 + row < N_NODES) v = *(const float4*)(x + (size_t)(node0 + row) * F_IN + c4 * 4);
            ushort4 b;
            b.x = f2bf(v.x); b.y = f2bf(v.y); b.z = f2bf(v.z); b.w = f2bf(v.w);
            *(ushort4*)&xsb[row][c4 * 4] = b;
        }
        __syncthreads();
        int lane = t & 63, wv = t >> 6;
        int lrow = lane & 15, lk = lane >> 4;
        // ---- MFMA: 16 nodes x 32 cols per wave; K=128 in 4 k-tiles
        const char* abase = (const char*)&xsb[wv * 16 + lrow][0];
        f32x4 o[2];
        #pragma unroll
        for (int nt = 0; nt < 2; nt++) {
            f32x4 z = {};
            #pragma unroll
            for (int kt = 0; kt < 4; kt++) {
                bf16x8 af = *(const bf16x8*)(abase + kt * 64 + lk * 16);
                bf16x8 bfr = *(const bf16x8*)((const char*)&wet[nt * 16 + lrow][0] + kt * 64 + lk * 16);
                z = __builtin_amdgcn_mfma_f32_16x16x32_bf16(af, bfr, z, 0, 0, 0);
            }
            o[nt] = z;
        }
        float b0 = bl[lrow], b1v = bl[16 + lrow];
        float vsl[2][4], vdl[2][4];
        #pragma unroll
        for (int h = 0; h < 4; h++) {
            vsl[0][h] = vs[lrow][h];      vsl[1][h] = vs[16 + lrow][h];
            vdl[0][h] = vd[lrow][h];      vdl[1][h] = vd[16 + lrow][h];
        }
        #pragma unroll
        for (int r = 0; r < 4; r++) {
            int node = node0 + wv * 16 + lk * 4 + r;
            float h0v0 = o[0][r] + b0;
            float h0v1 = o[1][r] + b1v;
            if (node < N_NODES) {
                h0b[(size_t)node * HID + lrow]      = f2bf(h0v0);
                h0b[(size_t)node * HID + 16 + lrow] = f2bf(h0v1);
            }
            float p[4], qd[4];
            #pragma unroll
            for (int h = 0; h < 4; h++) {
                p[h]  = h0v0 * vsl[0][h] + h0v1 * vsl[1][h];
                qd[h] = h0v0 * vdl[0][h] + h0v1 * vdl[1][h];
            }
            #pragma unroll
            for (int mask = 1; mask <= 8; mask <<= 1) {
                #pragma unroll
                for (int h = 0; h < 4; h++) {
                    p[h]  += __shfl_xor(p[h],  mask, 64);
                    qd[h] += __shfl_xor(qd[h], mask, 64);
                }
            }
            if (lrow == 0 && node < N_NODES) {
                *(float4*)(as + node * 4) = make_float4(p[0], p[1], p[2], p[3]);
                *(float4*)(ad + node * 4) = make_float4(qd[0], qd[1], qd[2], qd[3]);
            }
        }
    } else {
        int e0 = (blockIdx.x - NB64) * EPB;
        for (int i = t; i < NBKT; i += 256) hist[i] = 0;
        __syncthreads();
        unsigned int p[16];
        int bb[16];
        #pragma unroll
        for (int i = 0; i < 16; i++) {
            int e = e0 + i * 256 + t;
            bb[i] = -1;
            if (e < N_EDGES) {
                int s = ei[e], d = ei[N_EDGES + e];
                p[i] = ((unsigned int)s << 8) | (unsigned int)(d & 255);
                bb[i] = d >> 8;
                atomicAdd(&hist[bb[i]], 1);
            }
        }
        __syncthreads();
        for (int i = t; i < NBKT; i += 256) {
            int c = hist[i];
            base[i] = i * CAP + (c ? atomicAdd(&gcnt[i], c) : 0);
            hist[i] = 0;
        }
        __syncthreads();
        #pragma unroll
        for (int i = 0; i < 16; i++) {
            if (bb[i] >= 0) {
                int off = atomicAdd(&hist[bb[i]], 1);
                pairs[base[bb[i]] + off] = p[i];
            }
        }
    }
}

// ================================================================ F2 = bucketB only (CSR build from pairs)
__global__ __launch_bounds__(256) void k_F2(const unsigned int* __restrict__ pairs,
                                            const int* __restrict__ gcnt,
                                            int* __restrict__ rowptr,
                                            int* __restrict__ esrc) {
    __shared__ int cnt[256];
    __shared__ int cur[256];
    __shared__ int wsum[4];
    int t = threadIdx.x;
    int b = blockIdx.x;
    int lane = t & 63, wv = t >> 6;
    int v0 = (t < NBKT && t < b) ? gcnt[t] : 0;
    #pragma unroll
    for (int mask = 1; mask < 64; mask <<= 1) v0 += __shfl_xor(v0, mask, 64);
    if (lane == 0) wsum[wv] = v0;
    __syncthreads();
    int base = wsum[0] + wsum[1] + wsum[2] + wsum[3];
    int n0 = b << 8;
    int cntb = gcnt[b];
    int s0 = b * CAP;
    cnt[t] = 0;
    __syncthreads();
    for (int i = t; i < cntb; i += 256) atomicAdd(&cnt[pairs[s0 + i] & 255], 1);
    __syncthreads();
    int v = cnt[t], x = v;
    #pragma unroll
    for (int off = 1; off < 64; off <<= 1) { int y = __shfl_up(x, off, 64); if (lane >= off) x += y; }
    __syncthreads();
    if (lane == 63) wsum[wv] = x;
    __syncthreads();
    int add = 0;
    for (int j = 0; j < wv; j++) add += wsum[j];
    int excl = base + (x - v) + add;
    cur[t] = excl;
    if (n0 + t < N_NODES) rowptr[n0 + t] = excl;
    if (b == 0 && t == 0) rowptr[N_NODES] = N_EDGES;
    __syncthreads();
    for (int i = t; i < cntb; i += 256) {
        unsigned int p = pairs[s0 + i];
        int pos = atomicAdd(&cur[p & 255], 1);
        esrc[pos] = (int)(p >> 8);
    }
}

// ================================================================ layer-1 gather: h0-aggregation (R9 structure —
// readlane/SGPR-base loads). Writes softmax-normalized per-head aggregates awb (bf16x2, [N,64] dwords).
__global__ __launch_bounds__(256) void k_gather1(const int* __restrict__ esrc,
                                                 const int* __restrict__ rowptr,
                                                 const unsigned int* __restrict__ h0b,  // bf16x2 [N,16] dwords
                                                 const float* __restrict__ as,
                                                 const float* __restrict__ ad,
                                                 unsigned int* __restrict__ awb) {      // bf16x2 [N,64] dwords
    int t = threadIdx.x;
    int node = blockIdx.x * 4 + (t >> 6);
    int lane = t & 63;
    int head = lane >> 4;              // head owning this lane's channel pair
    int cp = lane & 15;                // k-pair 0..15 within the 32-dim h0 row
    int s16 = lane >> 2;               // weight slot 0..15
    int h4 = lane & 3;                 // weight head 0..3
    int lb = cp * 4;                   // byte offset of this lane's k-pair in a 64B row
    int hb = head * 4;                 // ds_bpermute byte base: src lane j*4+head
    int beg = rowptr[node], end = rowptr[node + 1];
    float ad_w = ad[node * 4 + h4];
    float ax = 0.f, ay = 0.f, s = 0.f;
    const char* hc = (const char*)h0b;
    for (int k = beg; k < end; k += 16) {
        int idx = k + s16;
        int sm = esrc[min(idx, end - 1)];
        // ---- issue 16 feature-row loads first (SGPR base + shared lane offset)
#define G1L(J) int sj##J = __builtin_amdgcn_readlane(sm, (J) * 4); \
        unsigned int u##J = *(const unsigned int*)(hc + (size_t)(unsigned)sj##J * 64 + lb);
        G1L(0)  G1L(1)  G1L(2)  G1L(3)  G1L(4)  G1L(5)  G1L(6)  G1L(7)
        G1L(8)  G1L(9)  G1L(10) G1L(11) G1L(12) G1L(13) G1L(14) G1L(15)
#undef G1L
        // ---- weight compute overlaps the loads
        float wm = edge_w(as[sm * 4 + h4], ad_w);
        if (idx >= end) wm = 0.f;                 // tail masking at source lane
        int wmi = __float_as_int(wm);
#define G1W(J) float w##J = __int_as_float(__builtin_amdgcn_ds_bpermute(hb + (J) * 16, wmi));
        G1W(0)  G1W(1)  G1W(2)  G1W(3)  G1W(4)  G1W(5)  G1W(6)  G1W(7)
        G1W(8)  G1W(9)  G1W(10) G1W(11) G1W(12) G1W(13) G1W(14) G1W(15)
#undef G1W
        ax += bf_lo(u0)  * w0  + bf_lo(u1)  * w1  + bf_lo(u2)  * w2  + bf_lo(u3)  * w3
            + bf_lo(u4)  * w4  + bf_lo(u5)  * w5  + bf_lo(u6)  * w6  + bf_lo(u7)  * w7
            + bf_lo(u8)  * w8  + bf_lo(u9)  * w9  + bf_lo(u10) * w10 + bf_lo(u11) * w11
            + bf_lo(u12) * w12 + bf_lo(u13) * w13 + bf_lo(u14) * w14 + bf_lo(u15) * w15;
        ay += bf_hi(u0)  * w0  + bf_hi(u1)  * w1  + bf_hi(u2)  * w2  + bf_hi(u3)  * w3
            + bf_hi(u4)  * w4  + bf_hi(u5)  * w5  + bf_hi(u6)  * w6  + bf_hi(u7)  * w7
            + bf_hi(u8)  * w8  + bf_hi(u9)  * w9  + bf_hi(u10) * w10 + bf_hi(u11) * w11
            + bf_hi(u12) * w12 + bf_hi(u13) * w13 + bf_hi(u14) * w14 + bf_hi(u15) * w15;
        s += (w0 + w1 + w2 + w3) + (w4 + w5 + w6 + w7)
           + (w8 + w9 + w10 + w11) + (w12 + w13 + w14 + w15);
    }
    float rs = 1.0f / (s + 1e-16f);
    awb[(size_t)node * 64 + lane] = ((unsigned int)f2bf(ay * rs) << 16) | (unsigned int)f2bf(ax * rs);
}

// ================================================================ k_h12: fused layer-1 epilogue + layer-2 GEMM (MFMA).
__global__ __launch_bounds__(256) void k_h12(const unsigned int* __restrict__ awb,  // [N,64] dwords
                                             const float* __restrict__ W1,          // [32][128] f32
                                             const float* __restrict__ b1,          // [128]
                                             const float* __restrict__ W2,          // [128][64] f32
                                             const float* __restrict__ a_src,
                                             const float* __restrict__ a_dst,
                                             unsigned short* __restrict__ h2,
                                             float* __restrict__ as, float* __restrict__ ad) {
    __shared__ unsigned int xsu[64][68];       // pass-1 A tile (awb); reused as out1 tile (ushort [64][136])
    __shared__ unsigned short w1t[128][40];    // [outch][k_h0] bf16 (W1^T)
    __shared__ unsigned short w2t[64][136];    // [n][k] bf16 (W2^T)
    __shared__ float b1s[128];
    int t = threadIdx.x;
    int node0 = blockIdx.x * 64;
    if (t < 128) b1s[t] = b1[t];
    #pragma unroll
    for (int it = 0; it < 4; it++) {
        int idx = it * 256 + t;
        int row = idx >> 4, c4 = idx & 15;
        uint4 v = make_uint4(0u, 0u, 0u, 0u);
        if (node0 + row < N_NODES) v = *(const uint4*)(awb + (size_t)(node0 + row) * 64 + c4 * 4);
        *(uint4*)&xsu[row][c4 * 4] = v;
    }
    #pragma unroll
    for (int it = 0; it < 16; it++) {
        int idx = it * 256 + t;
        int k = idx >> 7, n = idx & 127;
        w1t[n][k] = f2bf(W1[idx]);
    }
    #pragma unroll
    for (int it = 0; it < 8; it++) {
        int idx = it * 256 + t;
        int k = idx >> 4, n4 = idx & 15;
        float4 w = *(const float4*)(W2 + k * 64 + n4 * 4);
        w2t[n4 * 4 + 0][k] = f2bf(w.x);
        w2t[n4 * 4 + 1][k] = f2bf(w.y);
        w2t[n4 * 4 + 2][k] = f2bf(w.z);
        w2t[n4 * 4 + 3][k] = f2bf(w.w);
    }
    __syncthreads();
    int lane = t & 63, wv = t >> 6;
    int lrow = lane & 15, lk = lane >> 4;
    const char* abase = (const char*)&xsu[wv * 16 + lrow][0];
    f32x4 o1[8];
    #pragma unroll
    for (int nt = 0; nt < 8; nt++) {
        int kt = nt >> 1;
        bf16x8 af = *(const bf16x8*)(abase + kt * 64 + lk * 16);
        bf16x8 bf1 = *(const bf16x8*)((const char*)&w1t[nt * 16 + lrow][0] + lk * 16);
        f32x4 z = {};
        o1[nt] = __builtin_amdgcn_mfma_f32_16x16x32_bf16(af, bf1, z, 0, 0, 0);
    }
    __syncthreads();
    unsigned short* o1t = (unsigned short*)&xsu[0][0];
    #pragma unroll
    for (int nt = 0; nt < 8; nt++) {
        float bb = b1s[nt * 16 + lrow];
        #pragma unroll
        for (int r = 0; r < 4; r++) {
            int noderow = wv * 16 + lk * 4 + r;
            float v = o1[nt][r] + bb;
            v = (v > 0.f) ? v : (__expf(v) - 1.0f);   // ELU
            o1t[noderow * 136 + nt * 16 + lrow] = f2bf(v);
        }
    }
    __syncthreads();
    f32x4 acc[4] = {};
    const char* xbase = (const char*)&o1t[(wv * 16 + lrow) * 136];
    #pragma unroll
    for (int kt = 0; kt < 4; kt++) {
        bf16x8 af = *(const bf16x8*)(xbase + kt * 64 + lk * 16);
        #pragma unroll
        for (int h = 0; h < 4; h++) {
            bf16x8 bfr = *(const bf16x8*)((const char*)&w2t[h * 16 + lrow][0] + kt * 64 + lk * 16);
            acc[h] = __builtin_amdgcn_mfma_f32_16x16x32_bf16(af, bfr, acc[h], 0, 0, 0);
        }
    }
    float av[4], dv[4];
    #pragma unroll
    for (int h = 0; h < 4; h++) { av[h] = a_src[h * 16 + lrow]; dv[h] = a_dst[h * 16 + lrow]; }
    #pragma unroll
    for (int r = 0; r < 4; r++) {
        int node = node0 + wv * 16 + lk * 4 + r;
        float psh[4], pdh[4];
        #pragma unroll
        for (int h = 0; h < 4; h++) {
            float v = acc[h][r];
            if (node < N_NODES) h2[(size_t)node * 64 + h * 16 + lrow] = f2bf(v);
            float p = v * av[h], qv = v * dv[h];
            #pragma unroll
            for (int mask = 1; mask < 16; mask <<= 1) {
                p += __shfl_xor(p, mask, 64);
                qv += __shfl_xor(qv, mask, 64);
            }
            psh[h] = p; pdh[h] = qv;
        }
        if (lrow == 0 && node < N_NODES) {
            *(float4*)(as + node * 4) = make_float4(psh[0], psh[1], psh[2], psh[3]);
            *(float4*)(ad + node * 4) = make_float4(pdh[0], pdh[1], pdh[2], pdh[3]);
        }
    }
}

// ================================================================ layer-2 gather + head-mean + b2 + log_softmax
// (R9 structure — readlane/SGPR-base loads)
__global__ __launch_bounds__(256) void k_gather2(const int* __restrict__ esrc,
                                                 const int* __restrict__ rowptr,
                                                 const unsigned short* __restrict__ h2,  // bf16
                                                 const float* __restrict__ as,
                                                 const float* __restrict__ ad,
                                                 const float* __restrict__ b2,
                                                 float* __restrict__ out) {
    int t = threadIdx.x;
    int node = blockIdx.x * 4 + (t >> 6);
    int lane = t & 63;
    int head = lane >> 4, c = lane & 15;
    int s16 = lane >> 2;
    int h4 = lane & 3;
    int lb = lane * 2;                 // byte offset of this lane's channel in a 128B row
    int hb = head * 4;
    int beg = rowptr[node], end = rowptr[node + 1];
    float ad_w = ad[node * 4 + h4];
    float acc = 0.f, s = 0.f;
    const char* h2c = (const char*)h2;
    for (int k = beg; k < end; k += 16) {
        int idx = k + s16;
        int sm = esrc[min(idx, end - 1)];
#define G2L(J) int sj##J = __builtin_amdgcn_readlane(sm, (J) * 4); \
        float r##J = bf2f(*(const unsigned short*)(h2c + (size_t)(unsigned)sj##J * 128 + lb));
        G2L(0)  G2L(1)  G2L(2)  G2L(3)  G2L(4)  G2L(5)  G2L(6)  G2L(7)
        G2L(8)  G2L(9)  G2L(10) G2L(11) G2L(12) G2L(13) G2L(14) G2L(15)
#undef G2L
        float wm = edge_w(as[sm * 4 + h4], ad_w);
        if (idx >= end) wm = 0.f;
        int wmi = __float_as_int(wm);
#define G2W(J) float w##J = __int_as_float(__builtin_amdgcn_ds_bpermute(hb + (J) * 16, wmi));
        G2W(0)  G2W(1)  G2W(2)  G2W(3)  G2W(4)  G2W(5)  G2W(6)  G2W(7)
        G2W(8)  G2W(9)  G2W(10) G2W(11) G2W(12) G2W(13) G2W(14) G2W(15)
#undef G2W
        acc += r0 * w0 + r1 * w1 + r2 * w2 + r3 * w3
             + r4 * w4 + r5 * w5 + r6 * w6 + r7 * w7
             + r8 * w8 + r9 * w9 + r10 * w10 + r11 * w11
             + r12 * w12 + r13 * w13 + r14 * w14 + r15 * w15;
        s += (w0 + w1 + w2 + w3) + (w4 + w5 + w6 + w7)
           + (w8 + w9 + w10 + w11) + (w12 + w13 + w14 + w15);
    }
    float v = acc * (1.0f / (s + 1e-16f));
    v += __shfl_xor(v, 16, 64);          // mean over 4 heads
    v += __shfl_xor(v, 32, 64);
    v = v * 0.25f + b2[c];
    float m = v;                         // log_softmax over 16 classes
    #pragma unroll
    for (int mask = 1; mask < 16; mask <<= 1) m = fmaxf(m, __shfl_xor(m, mask, 64));
    float ex = __expf(v - m);
    float se = ex;
    #pragma unroll
    for (int mask = 1; mask < 16; mask <<= 1) se += __shfl_xor(se, mask, 64);
    float res = (v - m) - __logf(se);
    if (lane < 16) out[(size_t)node * 16 + lane] = res;
}

// ================================================================ host
extern "C" void kernel_launch(void* const* d_in, const int* in_sizes, int n_in,
                              void* d_out, int out_size, void* d_ws, size_t ws_size,
                              hipStream_t stream) {
    const float* x      = (const float*)d_in[0];
    const int*   ei     = (const int*)d_in[1];
    const float* Wemb   = (const float*)d_in[2];
    const float* bemb   = (const float*)d_in[3];
    const float* W1     = (const float*)d_in[4];
    const float* a_src1 = (const float*)d_in[5];
    const float* a_dst1 = (const float*)d_in[6];
    const float* b1     = (const float*)d_in[7];
    const float* W2     = (const float*)d_in[8];
    const float* a_src2 = (const float*)d_in[9];
    const float* a_dst2 = (const float*)d_in[10];
    const float* b2     = (const float*)d_in[11];
    float* out = (float*)d_out;

    char* ws = (char*)d_ws;
    size_t off = 0;
    auto alloc = [&](size_t bytes) { char* p = ws + off; off += (bytes + 255) & ~size_t(255); return p; };
    unsigned short* h2b   = (unsigned short*)alloc((size_t)N_NODES * 64 * 2);   // [N,64] bf16
    unsigned int*   awb   = (unsigned int*)alloc((size_t)N_NODES * 64 * 4);     // bf16x2 [N,128] aggregates
    unsigned short* h0b = (unsigned short*)alloc((size_t)N_NODES * HID * 2);    // [N,32] bf16
    int*          esrc  = (int*)alloc((size_t)N_EDGES * 4 + 64);
    unsigned int* pairs = (unsigned int*)alloc((size_t)NBKT * CAP * 4);
    float* as     = (float*)alloc((size_t)N_NODES * 4 * 4);
    float* ad     = (float*)alloc((size_t)N_NODES * 4 * 4);
    int*   rowptr = (int*)alloc((size_t)(N_NODES + 1) * 4);
    int*   gcnt   = (int*)alloc((size_t)NBKT * 4);

    const int GB = N_NODES / 4;    // 12500

    hipMemsetAsync(gcnt, 0, (size_t)NBKT * 4, stream);
    k_F1<<<NB64 + NBKT, 256, 0, stream>>>(x, Wemb, bemb, W1, a_src1, a_dst1,
                                          h0b, as, ad, ei, gcnt, pairs);
    k_F2<<<NBKT, 256, 0, stream>>>(pairs, gcnt, rowptr, esrc);
    k_gather1<<<GB, 256, 0, stream>>>(esrc, rowptr, (const unsigned int*)h0b, as, ad, awb);
    k_h12<<<NB64, 256, 0, stream>>>(awb, W1, b1, W2, a_src2, a_dst2, h2b, as, ad);
    k_gather2<<<GB, 256, 0, stream>>>(esrc, rowptr, h2b, as, ad, b2, out);
}